// Round 6
// baseline (954.254 us; speedup 1.0000x reference)
//
#include <hip/hip_runtime.h>
#include <stdint.h>

typedef __bf16 bf16_t;
typedef _Float16 fp16_t;
typedef bf16_t bf16x8 __attribute__((ext_vector_type(8)));
typedef fp16_t fp16x4 __attribute__((ext_vector_type(4)));
typedef float f32x4 __attribute__((ext_vector_type(4)));

#define LOG2E 1.44269504088896340736f

__device__ __forceinline__ float sigm(float x) {
    return __builtin_amdgcn_rcpf(1.f + __builtin_amdgcn_exp2f(-LOG2E * x));
}
__device__ __forceinline__ float tanh_(float x) {
    return 1.f - 2.f * __builtin_amdgcn_rcpf(1.f + __builtin_amdgcn_exp2f((2.f * LOG2E) * x));
}

template <int CTRL>
__device__ __forceinline__ float dpp_add(float x) {
    int perm = __builtin_amdgcn_update_dpp(0, __float_as_int(x), CTRL, 0xF, 0xF, true);
    return x + __int_as_float(perm);
}
// Sum across the 16 lanes of a DPP row (our lm group). All lanes get the sum.
__device__ __forceinline__ float red16(float x) {
    x = dpp_add<0xB1>(x);    // quad_perm [1,0,3,2]  : xor 1
    x = dpp_add<0x4E>(x);    // quad_perm [2,3,0,1]  : xor 2
    x = dpp_add<0x124>(x);   // row_ror:4
    x = dpp_add<0x128>(x);   // row_ror:8
    return x;
}

// Coherent (agent-scope, per-instruction sc0/sc1) loads of producer data.
__device__ __forceinline__ fp16x4 ldg_coh8(const fp16_t* p) {
    unsigned long long v = __hip_atomic_load((const unsigned long long*)p,
                                             __ATOMIC_RELAXED, __HIP_MEMORY_SCOPE_AGENT);
    union { unsigned long long u; fp16x4 f; } c; c.u = v; return c.f;
}

// Consumer gate with register watermark (see R4 notes).
__device__ __forceinline__ void gate_chunk(const int* fp, int need, int cn,
                                           int tid, int* wml, int& wmr) {
    if (cn < wmr) return;
    if (tid == 0) {
        while (__hip_atomic_load(fp + cn, __ATOMIC_RELAXED, __HIP_MEMORY_SCOPE_AGENT) < need)
            __builtin_amdgcn_s_sleep(2);
        int ah = cn + 16; if (ah > 127) ah = 127;
        int nw = (__hip_atomic_load(fp + ah, __ATOMIC_RELAXED, __HIP_MEMORY_SCOPE_AGENT) >= need)
                     ? ah + 1 : cn + 1;
        *wml = nw;
    }
    __syncthreads();
    wmr = *wml;
}

// ---------------------------------------------------------------------------
// Kernel 1: fold fuse_W2@fuse_W1 into one 340-vector + scalar, and build the
// zero-padded emotient Whh (128x32, real 80x20 embedded) for the MFMA path.
// ---------------------------------------------------------------------------
__global__ void prep_fuse(const float* __restrict__ W1, const float* __restrict__ b1,
                          const float* __restrict__ W2, const float* __restrict__ b2,
                          const float* __restrict__ whhE,
                          float* __restrict__ v, float* __restrict__ we32) {
    int u = threadIdx.x;
    if (u < 340) {
        float s = 0.f;
        for (int j = 0; j < 64; j++) s += W2[j] * W1[j * 340 + u];
        v[u] = s;
    } else if (u == 340) {
        float s = 0.f;
        for (int j = 0; j < 64; j++) s += W2[j] * b1[j];
        v[340] = s + b2[0];
    }
    for (int i = u; i < 4096; i += 512) {
        int n = i >> 5, k = i & 31;
        int g = n >> 5, uu = n & 31;
        we32[i] = (uu < 20 && k < 20) ? whhE[(g * 20 + uu) * 20 + k] : 0.f;
    }
}

// ---------------------------------------------------------------------------
// GEMM body. BM=256 rows = one t-chunk of 4 t x 64 b (t-major), BN=128,
// BK=32, split-bf16 A. xg store row-linear. Flag per (mod, chunk).
// E (hshift==0): output row is 128 wide; cols >= nW(80) written as ZERO so
// the padded h-units stay finite for the rec MFMA.
// ---------------------------------------------------------------------------
struct ModGemm {
    const float* x; const float* w; const float* bih; const float* bhh; fp16_t* xg;
    int D; int KB; int N4; int hshift; int nW;   // N4 = out stride; nW = real W rows
};
struct ModRec {
    const float* whh; const int* present; const fp16_t* xg;
    int voff; int vlim;
};
struct MegaArgs {
    ModGemm gm[4];
    int slot_mi[11]; int slot_nb[11];
    ModRec rm[4];
    const float* vvec;
    float* s_out;    // [4 mods][8 waves][64 b][512 t]
    int* flags;      // [4][128]
    int need[4];     // gemm blocks per chunk per mod (L4,E1,A2,I4)
};

__device__ void gemm_body(const ModGemm mg, int nb, int bm, int mi,
                          int* __restrict__ flags, int tid,
                          bf16_t* sAh, bf16_t* sAl, bf16_t* sB) {
    const int ncol0 = nb << 7;
    const int w = tid >> 6, l = tid & 63, lm = l & 15, q = l >> 4;
    const int wm = w & 3, wn = w >> 2;        // wave tile: 64 rows x 64 cols
    const int D = mg.D, N4 = mg.N4, nW = mg.nW;
    const int ra = tid >> 1, ca = (tid & 1) << 4;   // A: 2 thr/row, 16 cols
    const int rb = tid >> 2, cb = (tid & 3) << 3;   // B: 4 thr/row, 8 cols

    f32x4 acc[4][4];
#pragma unroll
    for (int a = 0; a < 4; a++)
#pragma unroll
        for (int b = 0; b < 4; b++) acc[a][b] = 0.f;

    for (int kb = 0; kb < mg.KB; kb++) {
        const int k0 = kb << 5;
        // ---- stage A (x): 256 rows (4 t x 64 b), hi/lo split
        {
            long row = (long)(bm << 8) + ra;
            int tt = (int)(row >> 6), bb = (int)(row & 63);
            const float* base = mg.x + ((size_t)bb * 512 + tt) * D;
            const float* src = base + k0 + ca;
            union { bf16_t e[16]; bf16x8 v[2]; } uh, ul;
            if (k0 + ca + 16 <= D) {
#pragma unroll
                for (int j = 0; j < 16; j += 2) {
                    float2 f = *(const float2*)(src + j);
                    bf16_t h0 = (bf16_t)f.x, h1 = (bf16_t)f.y;
                    uh.e[j] = h0; uh.e[j + 1] = h1;
                    ul.e[j] = (bf16_t)(f.x - (float)h0);
                    ul.e[j + 1] = (bf16_t)(f.y - (float)h1);
                }
            } else {
#pragma unroll
                for (int j = 0; j < 16; j++) {
                    int k = k0 + ca + j;
                    float fv = (k < D) ? base[k] : 0.f;
                    bf16_t h0 = (bf16_t)fv;
                    uh.e[j] = h0; ul.e[j] = (bf16_t)(fv - (float)h0);
                }
            }
            *(bf16x8*)&sAh[ra * 40 + ca] = uh.v[0];
            *(bf16x8*)&sAh[ra * 40 + ca + 8] = uh.v[1];
            *(bf16x8*)&sAl[ra * 40 + ca] = ul.v[0];
            *(bf16x8*)&sAl[ra * 40 + ca + 8] = ul.v[1];
        }
        // ---- stage B (W_ih strip): 128 x 32
        {
            int wrow = ncol0 + rb;
            bool vr = wrow < nW;
            const float* src = mg.w + (long)wrow * D + k0 + cb;
            union { bf16_t e[8]; bf16x8 v; } ub;
            if (vr && (k0 + cb + 8 <= D)) {
#pragma unroll
                for (int j = 0; j < 8; j += 2) {
                    float2 f = *(const float2*)(src + j);
                    ub.e[j] = (bf16_t)f.x; ub.e[j + 1] = (bf16_t)f.y;
                }
            } else {
#pragma unroll
                for (int j = 0; j < 8; j++) {
                    int k = k0 + cb + j;
                    ub.e[j] = (vr && k < D) ? (bf16_t)mg.w[(long)wrow * D + k] : (bf16_t)0.f;
                }
            }
            *(bf16x8*)&sB[rb * 40 + cb] = ub.v;
        }
        __syncthreads();
        bf16x8 ah[4], al[4];
#pragma unroll
        for (int mt = 0; mt < 4; mt++) {
            int row = (wm << 6) + (mt << 4) + lm;
            ah[mt] = *(const bf16x8*)&sAh[row * 40 + (q << 3)];
            al[mt] = *(const bf16x8*)&sAl[row * 40 + (q << 3)];
        }
#pragma unroll
        for (int nt = 0; nt < 4; nt++) {
            bf16x8 bfv = *(const bf16x8*)&sB[((wn << 6) + (nt << 4) + lm) * 40 + (q << 3)];
#pragma unroll
            for (int mt = 0; mt < 4; mt++) {
                acc[mt][nt] = __builtin_amdgcn_mfma_f32_16x16x32_bf16(ah[mt], bfv, acc[mt][nt], 0, 0, 0);
                acc[mt][nt] = __builtin_amdgcn_mfma_f32_16x16x32_bf16(al[mt], bfv, acc[mt][nt], 0, 0, 0);
            }
        }
        __syncthreads();
    }
    // ---- epilogue: +(b_ih+b_hh), store fp16 gate-interleaved (row-linear)
#pragma unroll
    for (int nt = 0; nt < 4; nt++) {
        int col = ncol0 + (wn << 6) + (nt << 4) + lm;
        if (col >= N4) continue;
        bool real = col < nW;
        float bias = real ? (mg.bih[col] + mg.bhh[col]) : 0.f;
        int colout;
        if (mg.hshift) colout = ((col & ((1 << mg.hshift) - 1)) << 2) | (col >> mg.hshift);
        else if (real) colout = ((col % 20) << 2) | (col / 20);   // E map
        else           colout = col;                               // E pad: zero
#pragma unroll
        for (int mt = 0; mt < 4; mt++) {
#pragma unroll
            for (int r = 0; r < 4; r++) {
                long row = (long)(bm << 8) + (wm << 6) + (mt << 4) + (q << 2) + r;
                float val = real ? (acc[mt][nt][r] + bias) : 0.f;
                mg.xg[(size_t)row * N4 + colout] = (fp16_t)val;
            }
        }
    }
    // ---- completion: barrier drains stores, tid0 release-add the flag.
    __syncthreads();
    if (tid == 0) {
        __hip_atomic_fetch_add(&flags[mi * 128 + bm], 1, __ATOMIC_RELEASE,
                               __HIP_MEMORY_SCOPE_AGENT);
    }
}

// ---------------------------------------------------------------------------
// Recurrent scan (16 blocks = 4 mods x 4 batch-groups of 16). All mods on the
// MFMA path now (E padded to H=32).
// ---------------------------------------------------------------------------
template <int H>
__device__ __forceinline__ void rec_step(
    int t, bool act, int w, int lm, int q, int b0,
    const bf16x8 (&wf)[4][H / 32], float vv,
    fp16x4 (&xvs)[4], const fp16_t* const (&px)[4], size_t tstride,
    float (&h_st)[4], float (&c_st)[4],
    const unsigned (&pw)[4], const bf16_t* __restrict__ hbR,
    bf16_t* __restrict__ hbW, float* __restrict__ s_out) {
    constexpr int KT = H / 32, Hp = H + 8;
    if (act) {
        bf16x8 af[KT];
#pragma unroll
        for (int kt = 0; kt < KT; kt++)
            af[kt] = *(const bf16x8*)&hbR[lm * Hp + (kt << 5) + (q << 3)];
        f32x4 accv[4];
#pragma unroll
        for (int g = 0; g < 4; g++)
#pragma unroll
            for (int r = 0; r < 4; r++)
                accv[g][r] = (float)xvs[r][g];
        int tn = t + 4;
        if (tn < 512) {
#pragma unroll
            for (int r = 0; r < 4; r++)
                xvs[r] = ldg_coh8(px[r] + (size_t)tn * tstride);
        }
#pragma unroll
        for (int kt = 0; kt < KT; kt++)
#pragma unroll
            for (int g = 0; g < 4; g++)
                accv[g] = __builtin_amdgcn_mfma_f32_16x16x32_bf16(af[kt], wf[g][kt], accv[g], 0, 0, 0);
        float cr[4];
#pragma unroll
        for (int r = 0; r < 4; r++) {
            float gi = sigm(accv[0][r]);
            float gf = sigm(accv[1][r]);
            float gg = tanh_(accv[2][r]);
            float go = sigm(accv[3][r]);
            float cn = gf * c_st[r] + gi * gg;
            float hn = go * tanh_(cn);
            bool pb = ((pw[r] >> (t & 31)) & 1u) != 0u;
            h_st[r] = pb ? hn : h_st[r];
            c_st[r] = pb ? cn : c_st[r];
            cr[r] = h_st[r] * vv;
        }
        const int u = (w << 4) + lm;
#pragma unroll
        for (int r = 0; r < 4; r++)
            hbW[((q << 2) + r) * Hp + u] = (bf16_t)h_st[r];
#pragma unroll
        for (int r = 0; r < 4; r++)
            cr[r] = red16(cr[r]);
        if (lm == 0) {
#pragma unroll
            for (int r = 0; r < 4; r++)
                s_out[(size_t)((w << 6) + b0 + (q << 2) + r) * 512 + t] = cr[r];
        }
    }
    __syncthreads();
}

template <int H>
__device__ void rec_mfma(const ModRec M, int grp, float* __restrict__ s_out,
                         const float* __restrict__ vvec,
                         const int* __restrict__ flagp, int need,
                         unsigned* presw, bf16_t* hb0, bf16_t* hb1, int* wml, int tid) {
    constexpr int KT = H / 32, TPG = H / 16, Hp = H + 8;
    const int N4 = 4 * H;
    const int w = tid >> 6, l = tid & 63, lm = l & 15, q = l >> 4;
    const int b0 = grp << 4;
    const bool act = (w < TPG);

    for (int i = tid; i < 16 * Hp; i += 512) { hb0[i] = (bf16_t)0.f; hb1[i] = (bf16_t)0.f; }
    // pack present bits: presw[row][word]  (16 rows x 16 words x 32 bits)
    for (int i = tid; i < 256; i += 512) {
        const int* ps = M.present + ((b0 + (i >> 4)) << 9) + ((i & 15) << 5);
        unsigned bits = 0u;
#pragma unroll
        for (int j = 0; j < 32; j++) bits |= (unsigned)(ps[j] != 0) << j;
        presw[i] = bits;
    }

    bf16x8 wf[4][KT];
    float vv = 0.f;
    const int u = (w << 4) + lm;
    if (act) {
#pragma unroll
        for (int g = 0; g < 4; g++) {
            int n = g * H + u;
#pragma unroll
            for (int kt = 0; kt < KT; kt++) {
                int k = (kt << 5) + (q << 3);
                const float* sp_ = M.whh + (long)n * H + k;
                float4 f0 = *(const float4*)sp_;
                float4 f1 = *(const float4*)(sp_ + 4);
                union { bf16_t e[8]; bf16x8 v; } uu;
                uu.e[0] = (bf16_t)f0.x; uu.e[1] = (bf16_t)f0.y;
                uu.e[2] = (bf16_t)f0.z; uu.e[3] = (bf16_t)f0.w;
                uu.e[4] = (bf16_t)f1.x; uu.e[5] = (bf16_t)f1.y;
                uu.e[6] = (bf16_t)f1.z; uu.e[7] = (bf16_t)f1.w;
                wf[g][kt] = uu.v;
            }
        }
        vv = (u < M.vlim) ? vvec[M.voff + u] : 0.f;
    }
    const fp16_t* px[4];
#pragma unroll
    for (int r = 0; r < 4; r++)
        px[r] = M.xg + (size_t)(b0 + (q << 2) + r) * N4 + (u << 2);
    const size_t tstride = (size_t)64 * N4;

    int wmr = 0;
    gate_chunk(flagp, need, 0, tid, wml, wmr);   // xg chunk 0 ready

    fp16x4 xv[4][4];   // [slot][r]
    if (act) {
#pragma unroll
        for (int s = 0; s < 4; s++)
#pragma unroll
            for (int r = 0; r < 4; r++)
                xv[s][r] = ldg_coh8(px[r] + (size_t)s * tstride);
    }
    float h_st[4] = {0, 0, 0, 0}, c_st[4] = {0, 0, 0, 0};
    unsigned pw[4] = {0, 0, 0, 0};
    __syncthreads();

    for (int t0 = 0; t0 < 512; t0 += 4) {
        int cn = (t0 >> 2) + 1;           // chunk touched by this iter's prefetch
        if (cn < 128) gate_chunk(flagp, need, cn, tid, wml, wmr);
        if ((t0 & 31) == 0 && act) {
            int wd = t0 >> 5;
#pragma unroll
            for (int r = 0; r < 4; r++)
                pw[r] = presw[(((q << 2) + r) << 4) + wd];
        }
        rec_step<H>(t0 + 0, act, w, lm, q, b0, wf, vv, xv[0], px, tstride, h_st, c_st, pw, hb0, hb1, s_out);
        rec_step<H>(t0 + 1, act, w, lm, q, b0, wf, vv, xv[1], px, tstride, h_st, c_st, pw, hb1, hb0, s_out);
        rec_step<H>(t0 + 2, act, w, lm, q, b0, wf, vv, xv[2], px, tstride, h_st, c_st, pw, hb0, hb1, s_out);
        rec_step<H>(t0 + 3, act, w, lm, q, b0, wf, vv, xv[3], px, tstride, h_st, c_st, pw, hb1, hb0, s_out);
    }
}

// ---------------------------------------------------------------------------
// Mega kernel: blocks 0..15 = rec (prio 3); blocks 16.. = gemm, XCD-aware
// mapping: all 11 slot-blocks of t-chunk c on XCD c%8 (see R5).
// ---------------------------------------------------------------------------
__global__ __launch_bounds__(512) void mega(MegaArgs A) {
    __shared__ __align__(16) char smem[51712];
    const int tid = threadIdx.x;
    const int bid = blockIdx.x;
    if (bid < 16) {
        __builtin_amdgcn_s_setprio(3);   // protect the serial critical path
        bf16_t*   hb0   = (bf16_t*)smem;                // 4352
        bf16_t*   hb1   = (bf16_t*)(smem + 4352);       // 4352
        unsigned* presw = (unsigned*)(smem + 8704);     // 1024
        int*      wml   = (int*)(smem + 9728);          // 4
        const int mi = bid >> 2, grp = bid & 3;         // 0=L,1=E,2=A,3=I
        const ModRec M = A.rm[mi];
        const int* flagp = A.flags + mi * 128;
        const int need = A.need[mi];
        float* s_out = A.s_out + (size_t)mi * 8 * 64 * 512;
        if (mi == 1)      rec_mfma<32>(M, grp, s_out, A.vvec, flagp, need, presw, hb0, hb1, wml, tid);
        else if (mi == 2) rec_mfma<64>(M, grp, s_out, A.vvec, flagp, need, presw, hb0, hb1, wml, tid);
        else              rec_mfma<128>(M, grp, s_out, A.vvec, flagp, need, presw, hb0, hb1, wml, tid);
    } else {
        bf16_t* sAh = (bf16_t*)smem;                    // 20480
        bf16_t* sAl = (bf16_t*)(smem + 20480);          // 20480
        bf16_t* sB  = (bf16_t*)(smem + 40960);          // 10240
        int e = bid - 16;            // 176 octets x 8 XCD lanes
        int x = e & 7;               // XCD lane (bid%8 round-robin, perf-only)
        int k = e >> 3;              // stream position on this XCD
        int bmi = (k / 11) * 8 + x;  // t-chunk — all 11 slots same XCD
        int slot = k % 11;
        int mi = A.slot_mi[slot];
        gemm_body(A.gm[mi], A.slot_nb[slot], bmi, mi, A.flags, tid, sAh, sAl, sB);
    }
}

// ---------------------------------------------------------------------------
// Kernel 4: out = mask * (sum of written partial slots + c0)
// slots: L:0-7, E:8-9, A:16-19, I:24-31
// ---------------------------------------------------------------------------
__global__ void fuse_out(const float* __restrict__ sp, const float* __restrict__ v,
                         const float* __restrict__ masks, float* __restrict__ out) {
    int i = threadIdx.x + blockIdx.x * 256;
    float c0 = v[340];
    float s = 0.f;
#pragma unroll
    for (int w = 0; w < 10; w++) s += sp[(size_t)w * 32768 + i];
#pragma unroll
    for (int w = 16; w < 20; w++) s += sp[(size_t)w * 32768 + i];
#pragma unroll
    for (int w = 24; w < 32; w++) s += sp[(size_t)w * 32768 + i];
    out[i] = masks[i] * (s + c0);
}

// ---------------------------------------------------------------------------
extern "C" void kernel_launch(void* const* d_in, const int* in_sizes, int n_in,
                              void* d_out, int out_size, void* d_ws, size_t ws_size,
                              hipStream_t stream) {
    const float* xL = (const float*)d_in[0];
    const int*   pL = (const int*)d_in[1];
    const float* WihL = (const float*)d_in[2];
    const float* WhhL = (const float*)d_in[3];
    const float* bihL = (const float*)d_in[4];
    const float* bhhL = (const float*)d_in[5];
    const float* xE = (const float*)d_in[6];
    const int*   pE = (const int*)d_in[7];
    const float* WihE = (const float*)d_in[8];
    const float* WhhE = (const float*)d_in[9];
    const float* bihE = (const float*)d_in[10];
    const float* bhhE = (const float*)d_in[11];
    const float* xA = (const float*)d_in[12];
    const int*   pA = (const int*)d_in[13];
    const float* WihA = (const float*)d_in[14];
    const float* WhhA = (const float*)d_in[15];
    const float* bihA = (const float*)d_in[16];
    const float* bhhA = (const float*)d_in[17];
    const float* xI = (const float*)d_in[18];
    const int*   pI = (const int*)d_in[19];
    const float* WihI = (const float*)d_in[20];
    const float* WhhI = (const float*)d_in[21];
    const float* bihI = (const float*)d_in[22];
    const float* bhhI = (const float*)d_in[23];
    const float* masks = (const float*)d_in[25];
    const float* fW1 = (const float*)d_in[26];
    const float* fb1 = (const float*)d_in[27];
    const float* fW2 = (const float*)d_in[28];
    const float* fb2 = (const float*)d_in[29];

    char* ws = (char*)d_ws;
    float* v     = (float*)ws;                           // 341 floats
    int*   flags = (int*)(ws + 4096);                    // 4*128 ints
    float* we32  = (float*)(ws + 8192);                  // 128*32 floats = 16 KB
    float* spart = (float*)(ws + (1 << 16));             // 32*32768 floats = 4 MB
    fp16_t* xgL = (fp16_t*)(ws + (1 << 16) + (4 << 20));
    fp16_t* xgE = xgL + (size_t)32768 * 512;
    fp16_t* xgA = xgE + (size_t)32768 * 128;             // E padded to 128-wide
    fp16_t* xgI = xgA + (size_t)32768 * 256;

    prep_fuse<<<dim3(1), dim3(512), 0, stream>>>(fW1, fb1, fW2, fb2, WhhE, v, we32);
    hipMemsetAsync(flags, 0, 4 * 128 * sizeof(int), stream);

    MegaArgs A;
    A.gm[0] = {xL, WihL, bihL, bhhL, xgL, 300,  10, 512, 7, 512};
    A.gm[1] = {xE, WihE, bihE, bhhE, xgE, 30,   1,  128, 0, 80};
    A.gm[2] = {xA, WihA, bihA, bhhA, xgA, 88,   3,  256, 6, 256};
    A.gm[3] = {xI, WihI, bihI, bhhI, xgI, 1000, 32, 512, 7, 512};
    // I first (largest A-panel gets tightest co-residency), then L, A, E.
    const int mi_tab[11] = {3, 3, 3, 3, 0, 0, 0, 0, 2, 2, 1};
    const int nb_tab[11] = {0, 1, 2, 3, 0, 1, 2, 3, 0, 1, 0};
    for (int i = 0; i < 11; i++) { A.slot_mi[i] = mi_tab[i]; A.slot_nb[i] = nb_tab[i]; }
    A.rm[0] = {WhhL, pL, xgL, 0,   128};
    A.rm[1] = {we32, pE, xgE, 128, 20};
    A.rm[2] = {WhhA, pA, xgA, 148, 64};
    A.rm[3] = {WhhI, pI, xgI, 212, 128};
    A.vvec = v;
    A.s_out = spart;
    A.flags = flags;
    A.need[0] = 4; A.need[1] = 1; A.need[2] = 2; A.need[3] = 4;

    mega<<<dim3(16 + 128 * 11), dim3(512), 0, stream>>>(A);

    fuse_out<<<dim3(128), dim3(256), 0, stream>>>(spart, v, masks, (float*)d_out);
}

// Round 7
// 921.980 us; speedup vs baseline: 1.0350x; 1.0350x over previous
//
#include <hip/hip_runtime.h>
#include <stdint.h>

typedef __bf16 bf16_t;
typedef _Float16 fp16_t;
typedef bf16_t bf16x8 __attribute__((ext_vector_type(8)));
typedef fp16_t fp16x4 __attribute__((ext_vector_type(4)));
typedef float f32x4 __attribute__((ext_vector_type(4)));

#define LOG2E 1.44269504088896340736f

__device__ __forceinline__ float sigm(float x) {
    return __builtin_amdgcn_rcpf(1.f + __builtin_amdgcn_exp2f(-LOG2E * x));
}
__device__ __forceinline__ float tanh_(float x) {
    return 1.f - 2.f * __builtin_amdgcn_rcpf(1.f + __builtin_amdgcn_exp2f((2.f * LOG2E) * x));
}

template <int CTRL>
__device__ __forceinline__ float dpp_add(float x) {
    int perm = __builtin_amdgcn_update_dpp(0, __float_as_int(x), CTRL, 0xF, 0xF, true);
    return x + __int_as_float(perm);
}
// Sum across the 16 lanes of a DPP row (our lm group). All lanes get the sum.
__device__ __forceinline__ float red16(float x) {
    x = dpp_add<0xB1>(x);    // quad_perm [1,0,3,2]  : xor 1
    x = dpp_add<0x4E>(x);    // quad_perm [2,3,0,1]  : xor 2
    x = dpp_add<0x124>(x);   // row_ror:4
    x = dpp_add<0x128>(x);   // row_ror:8
    return x;
}

// Coherent (agent-scope, sc0/sc1 per-instruction) loads of producer data.
__device__ __forceinline__ fp16x4 ldg_coh8(const fp16_t* p) {
    unsigned long long v = __hip_atomic_load((const unsigned long long*)p,
                                             __ATOMIC_RELAXED, __HIP_MEMORY_SCOPE_AGENT);
    union { unsigned long long u; fp16x4 f; } c; c.u = v; return c.f;
}
__device__ __forceinline__ fp16_t ldg_coh2(const fp16_t* p) {
    unsigned short v = __hip_atomic_load((const unsigned short*)p,
                                         __ATOMIC_RELAXED, __HIP_MEMORY_SCOPE_AGENT);
    union { unsigned short u; fp16_t f; } c; c.u = v; return c.f;
}

// Consumer gate with register watermark (see R4 notes).
__device__ __forceinline__ void gate_chunk(const int* fp, int need, int cn,
                                           int tid, int* wml, int& wmr) {
    if (cn < wmr) return;
    if (tid == 0) {
        while (__hip_atomic_load(fp + cn, __ATOMIC_RELAXED, __HIP_MEMORY_SCOPE_AGENT) < need)
            __builtin_amdgcn_s_sleep(2);
        int ah = cn + 16; if (ah > 127) ah = 127;
        int nw = (__hip_atomic_load(fp + ah, __ATOMIC_RELAXED, __HIP_MEMORY_SCOPE_AGENT) >= need)
                     ? ah + 1 : cn + 1;
        *wml = nw;
    }
    __syncthreads();
    wmr = *wml;
}

// ---------------------------------------------------------------------------
// Kernel 1: fold fuse_W2@fuse_W1 into a single 340-vector + scalar.
// ALSO zeroes the chunk flags (replaces hipMemsetAsync — a graph-captured
// memset node cost ~170us/replay; this is stream-ordered before mega).
// ---------------------------------------------------------------------------
__global__ void prep_fuse(const float* __restrict__ W1, const float* __restrict__ b1,
                          const float* __restrict__ W2, const float* __restrict__ b2,
                          float* __restrict__ v, int* __restrict__ flags) {
    int u = threadIdx.x;
    flags[u] = 0;   // 512 ints = 4*128 chunk flags
    if (u < 340) {
        float s = 0.f;
        for (int j = 0; j < 64; j++) s += W2[j] * W1[j * 340 + u];
        v[u] = s;
    } else if (u == 340) {
        float s = 0.f;
        for (int j = 0; j < 64; j++) s += W2[j] * b1[j];
        v[340] = s + b2[0];
    }
}

// ---------------------------------------------------------------------------
// GEMM body. BM=256 rows = one t-chunk of 4 t x 64 b (t-major), BN=128,
// BK=32, split-bf16 A. xg store is row-linear. Completion flag per (mod,bm).
// ---------------------------------------------------------------------------
struct ModGemm {
    const float* x; const float* w; const float* bih; const float* bhh; fp16_t* xg;
    int D; int KB; int N4; int hshift;
};
struct ModRec {
    const float* whh; const int* present; const fp16_t* xg;
    int N4; int voff;
};
struct MegaArgs {
    ModGemm gm[4];
    int slot_mi[11]; int slot_nb[11];
    ModRec rm[4];
    const float* vvec;
    float* s_out;    // [4 mods][8 waves][64 b][512 t]
    int* flags;      // [4][128]
    int need[4];     // gemm blocks per chunk per mod (L4,E1,A2,I4)
};

__device__ void gemm_body(const ModGemm mg, int nb, int bm, int mi,
                          int* __restrict__ flags, int tid,
                          bf16_t* sAh, bf16_t* sAl, bf16_t* sB) {
    const int ncol0 = nb << 7;
    const int w = tid >> 6, l = tid & 63, lm = l & 15, q = l >> 4;
    const int wm = w & 3, wn = w >> 2;        // wave tile: 64 rows x 64 cols
    const int D = mg.D, N4 = mg.N4;
    const int ra = tid >> 1, ca = (tid & 1) << 4;   // A: 2 thr/row, 16 cols
    const int rb = tid >> 2, cb = (tid & 3) << 3;   // B: 4 thr/row, 8 cols

    f32x4 acc[4][4];
#pragma unroll
    for (int a = 0; a < 4; a++)
#pragma unroll
        for (int b = 0; b < 4; b++) acc[a][b] = 0.f;

    for (int kb = 0; kb < mg.KB; kb++) {
        const int k0 = kb << 5;
        // ---- stage A (x): 256 rows (4 t x 64 b), hi/lo split
        {
            long row = (long)(bm << 8) + ra;
            int tt = (int)(row >> 6), bb = (int)(row & 63);
            const float* base = mg.x + ((size_t)bb * 512 + tt) * D;
            const float* src = base + k0 + ca;
            union { bf16_t e[16]; bf16x8 v[2]; } uh, ul;
            if (k0 + ca + 16 <= D) {
#pragma unroll
                for (int j = 0; j < 16; j += 2) {
                    float2 f = *(const float2*)(src + j);
                    bf16_t h0 = (bf16_t)f.x, h1 = (bf16_t)f.y;
                    uh.e[j] = h0; uh.e[j + 1] = h1;
                    ul.e[j] = (bf16_t)(f.x - (float)h0);
                    ul.e[j + 1] = (bf16_t)(f.y - (float)h1);
                }
            } else {
#pragma unroll
                for (int j = 0; j < 16; j++) {
                    int k = k0 + ca + j;
                    float fv = (k < D) ? base[k] : 0.f;
                    bf16_t h0 = (bf16_t)fv;
                    uh.e[j] = h0; ul.e[j] = (bf16_t)(fv - (float)h0);
                }
            }
            *(bf16x8*)&sAh[ra * 40 + ca] = uh.v[0];
            *(bf16x8*)&sAh[ra * 40 + ca + 8] = uh.v[1];
            *(bf16x8*)&sAl[ra * 40 + ca] = ul.v[0];
            *(bf16x8*)&sAl[ra * 40 + ca + 8] = ul.v[1];
        }
        // ---- stage B (W_ih strip): 128 x 32
        {
            int wrow = ncol0 + rb;
            bool vr = wrow < N4;
            const float* src = mg.w + (long)wrow * D + k0 + cb;
            union { bf16_t e[8]; bf16x8 v; } ub;
            if (vr && (k0 + cb + 8 <= D)) {
#pragma unroll
                for (int j = 0; j < 8; j += 2) {
                    float2 f = *(const float2*)(src + j);
                    ub.e[j] = (bf16_t)f.x; ub.e[j + 1] = (bf16_t)f.y;
                }
            } else {
#pragma unroll
                for (int j = 0; j < 8; j++) {
                    int k = k0 + cb + j;
                    ub.e[j] = (vr && k < D) ? (bf16_t)mg.w[(long)wrow * D + k] : (bf16_t)0.f;
                }
            }
            *(bf16x8*)&sB[rb * 40 + cb] = ub.v;
        }
        __syncthreads();
        bf16x8 ah[4], al[4];
#pragma unroll
        for (int mt = 0; mt < 4; mt++) {
            int row = (wm << 6) + (mt << 4) + lm;
            ah[mt] = *(const bf16x8*)&sAh[row * 40 + (q << 3)];
            al[mt] = *(const bf16x8*)&sAl[row * 40 + (q << 3)];
        }
#pragma unroll
        for (int nt = 0; nt < 4; nt++) {
            bf16x8 bfv = *(const bf16x8*)&sB[((wn << 6) + (nt << 4) + lm) * 40 + (q << 3)];
#pragma unroll
            for (int mt = 0; mt < 4; mt++) {
                acc[mt][nt] = __builtin_amdgcn_mfma_f32_16x16x32_bf16(ah[mt], bfv, acc[mt][nt], 0, 0, 0);
                acc[mt][nt] = __builtin_amdgcn_mfma_f32_16x16x32_bf16(al[mt], bfv, acc[mt][nt], 0, 0, 0);
            }
        }
        __syncthreads();
    }
    // ---- epilogue: +(b_ih+b_hh), store fp16 gate-interleaved (row-linear)
#pragma unroll
    for (int nt = 0; nt < 4; nt++) {
        int col = ncol0 + (wn << 6) + (nt << 4) + lm;
        if (col >= N4) continue;
        float bias = mg.bih[col] + mg.bhh[col];
        int colout = mg.hshift ? ((col & ((1 << mg.hshift) - 1)) << 2) | (col >> mg.hshift) : col;
#pragma unroll
        for (int mt = 0; mt < 4; mt++) {
#pragma unroll
            for (int r = 0; r < 4; r++) {
                long row = (long)(bm << 8) + (wm << 6) + (mt << 4) + (q << 2) + r;
                mg.xg[(size_t)row * N4 + colout] = (fp16_t)(acc[mt][nt][r] + bias);
            }
        }
    }
    // ---- completion: barrier drains stores, tid0 release-adds the flag.
    __syncthreads();
    if (tid == 0) {
        __hip_atomic_fetch_add(&flags[mi * 128 + bm], 1, __ATOMIC_RELEASE,
                               __HIP_MEMORY_SCOPE_AGENT);
    }
}

// ---------------------------------------------------------------------------
// Recurrent scan bodies (16 blocks = 4 mods x 4 batch-groups of 16).
// ---------------------------------------------------------------------------
template <int H>
__device__ __forceinline__ void rec_step(
    int t, bool act, int w, int lm, int q, int b0,
    const bf16x8 (&wf)[4][H / 32], float vv,
    fp16x4 (&xvs)[4], const fp16_t* const (&px)[4], size_t tstride,
    float (&h_st)[4], float (&c_st)[4],
    const unsigned (&pw)[4], const bf16_t* __restrict__ hbR,
    bf16_t* __restrict__ hbW, float* __restrict__ s_out) {
    constexpr int KT = H / 32, Hp = H + 8;
    if (act) {
        bf16x8 af[KT];
#pragma unroll
        for (int kt = 0; kt < KT; kt++)
            af[kt] = *(const bf16x8*)&hbR[lm * Hp + (kt << 5) + (q << 3)];
        f32x4 accv[4];
#pragma unroll
        for (int g = 0; g < 4; g++)
#pragma unroll
            for (int r = 0; r < 4; r++)
                accv[g][r] = (float)xvs[r][g];
        int tn = t + 4;
        if (tn < 512) {
#pragma unroll
            for (int r = 0; r < 4; r++)
                xvs[r] = ldg_coh8(px[r] + (size_t)tn * tstride);
        }
#pragma unroll
        for (int kt = 0; kt < KT; kt++)
#pragma unroll
            for (int g = 0; g < 4; g++)
                accv[g] = __builtin_amdgcn_mfma_f32_16x16x32_bf16(af[kt], wf[g][kt], accv[g], 0, 0, 0);
        float cr[4];
#pragma unroll
        for (int r = 0; r < 4; r++) {
            float gi = sigm(accv[0][r]);
            float gf = sigm(accv[1][r]);
            float gg = tanh_(accv[2][r]);
            float go = sigm(accv[3][r]);
            float cn = gf * c_st[r] + gi * gg;
            float hn = go * tanh_(cn);
            bool pb = ((pw[r] >> (t & 31)) & 1u) != 0u;
            h_st[r] = pb ? hn : h_st[r];
            c_st[r] = pb ? cn : c_st[r];
            cr[r] = h_st[r] * vv;
        }
        const int u = (w << 4) + lm;
#pragma unroll
        for (int r = 0; r < 4; r++)
            hbW[((q << 2) + r) * Hp + u] = (bf16_t)h_st[r];
#pragma unroll
        for (int r = 0; r < 4; r++)
            cr[r] = red16(cr[r]);
        if (lm == 0) {
#pragma unroll
            for (int r = 0; r < 4; r++)
                s_out[(size_t)((w << 6) + b0 + (q << 2) + r) * 512 + t] = cr[r];
        }
    }
    __syncthreads();
}

template <int H>
__device__ void rec_mfma(const ModRec M, int grp, float* __restrict__ s_out,
                         const float* __restrict__ vvec,
                         const int* __restrict__ flagp, int need,
                         unsigned* presw, bf16_t* hb0, bf16_t* hb1, int* wml, int tid) {
    constexpr int KT = H / 32, TPG = H / 16, Hp = H + 8;
    const int N4 = 4 * H;
    const int w = tid >> 6, l = tid & 63, lm = l & 15, q = l >> 4;
    const int b0 = grp << 4;
    const bool act = (w < TPG);

    for (int i = tid; i < 16 * Hp; i += 512) { hb0[i] = (bf16_t)0.f; hb1[i] = (bf16_t)0.f; }
    // pack present bits: presw[row][word]  (16 rows x 16 words x 32 bits)
    for (int i = tid; i < 256; i += 512) {
        const int* ps = M.present + ((b0 + (i >> 4)) << 9) + ((i & 15) << 5);
        unsigned bits = 0u;
#pragma unroll
        for (int j = 0; j < 32; j++) bits |= (unsigned)(ps[j] != 0) << j;
        presw[i] = bits;
    }

    bf16x8 wf[4][KT];
    float vv = 0.f;
    const int u = (w << 4) + lm;
    if (act) {
#pragma unroll
        for (int g = 0; g < 4; g++) {
            int n = g * H + u;
#pragma unroll
            for (int kt = 0; kt < KT; kt++) {
                int k = (kt << 5) + (q << 3);
                const float* sp_ = M.whh + (long)n * H + k;
                float4 f0 = *(const float4*)sp_;
                float4 f1 = *(const float4*)(sp_ + 4);
                union { bf16_t e[8]; bf16x8 v; } uu;
                uu.e[0] = (bf16_t)f0.x; uu.e[1] = (bf16_t)f0.y;
                uu.e[2] = (bf16_t)f0.z; uu.e[3] = (bf16_t)f0.w;
                uu.e[4] = (bf16_t)f1.x; uu.e[5] = (bf16_t)f1.y;
                uu.e[6] = (bf16_t)f1.z; uu.e[7] = (bf16_t)f1.w;
                wf[g][kt] = uu.v;
            }
        }
        vv = vvec[M.voff + u];
    }
    const fp16_t* px[4];
#pragma unroll
    for (int r = 0; r < 4; r++)
        px[r] = M.xg + (size_t)(b0 + (q << 2) + r) * N4 + (u << 2);
    const size_t tstride = (size_t)64 * N4;

    int wmr = 0;
    // wait for xg chunk 0 (t=0..3) before the initial prefetch
    gate_chunk(flagp, need, 0, tid, wml, wmr);

    fp16x4 xv[4][4];   // [slot][r]
    if (act) {
#pragma unroll
        for (int s = 0; s < 4; s++)
#pragma unroll
            for (int r = 0; r < 4; r++)
                xv[s][r] = ldg_coh8(px[r] + (size_t)s * tstride);
    }
    float h_st[4] = {0, 0, 0, 0}, c_st[4] = {0, 0, 0, 0};
    unsigned pw[4] = {0, 0, 0, 0};
    __syncthreads();

    for (int t0 = 0; t0 < 512; t0 += 4) {
        int cn = (t0 >> 2) + 1;           // chunk touched by this iter's prefetch
        if (cn < 128) gate_chunk(flagp, need, cn, tid, wml, wmr);
        if ((t0 & 31) == 0 && act) {
            int wd = t0 >> 5;
#pragma unroll
            for (int r = 0; r < 4; r++)
                pw[r] = presw[(((q << 2) + r) << 4) + wd];
        }
        rec_step<H>(t0 + 0, act, w, lm, q, b0, wf, vv, xv[0], px, tstride, h_st, c_st, pw, hb0, hb1, s_out);
        rec_step<H>(t0 + 1, act, w, lm, q, b0, wf, vv, xv[1], px, tstride, h_st, c_st, pw, hb1, hb0, s_out);
        rec_step<H>(t0 + 2, act, w, lm, q, b0, wf, vv, xv[2], px, tstride, h_st, c_st, pw, hb0, hb1, s_out);
        rec_step<H>(t0 + 3, act, w, lm, q, b0, wf, vv, xv[3], px, tstride, h_st, c_st, pw, hb1, hb0, s_out);
    }
}

// Emotient (H=20): fp32 VALU path, weights in registers, prefetch dist 4.
__device__ void rec_emot(const ModRec M, int grp, float* __restrict__ s_out,
                         const float* __restrict__ vvec,
                         const int* __restrict__ flagp, int need,
                         float* presf, float* gbuf /*16*81*/, float* he /*16*21*/,
                         int* wml, int tid) {
    const int b0 = grp << 4;
    for (int i = tid; i < 16 * 21; i += 512) he[i] = 0.f;
    for (int i = tid; i < 16 * 512; i += 512)
        presf[i] = (float)M.present[((b0 + (i >> 9)) << 9) + (i & 511)];
    const int bl = tid >> 5;       // 0..15
    const int j0 = tid & 31;
    const bool has2 = (j0 < 16);
    float wr0[20], wr1[20], wr2[20];
#pragma unroll
    for (int k = 0; k < 20; k++) {
        wr0[k] = M.whh[j0 * 20 + k];
        wr1[k] = M.whh[(j0 + 32) * 20 + k];
        wr2[k] = has2 ? M.whh[(j0 + 64) * 20 + k] : 0.f;
    }
    const int b2 = tid / 20, u2 = tid % 20;
    const bool p2 = (tid < 320);
    float c_st = 0.f, h_st = 0.f;
    const fp16_t* px = M.xg + (size_t)(b0 + bl) * 80;   // + t*64*80

    int wmr = 0;
    gate_chunk(flagp, need, 0, tid, wml, wmr);   // xg chunk 0 ready

    fp16_t e0[4], e1[4], e2[4];
#pragma unroll
    for (int s = 0; s < 4; s++) {
        const fp16_t* p = px + (size_t)s * 5120;
        e0[s] = ldg_coh2(p + j0);
        e1[s] = ldg_coh2(p + j0 + 32);
        e2[s] = has2 ? ldg_coh2(p + j0 + 64) : (fp16_t)0.f;
    }
    __syncthreads();

    for (int t0 = 0; t0 < 512; t0 += 4) {
        int cn = (t0 >> 2) + 1;
        if (cn < 128) gate_chunk(flagp, need, cn, tid, wml, wmr);
#pragma unroll
        for (int s = 0; s < 4; s++) {
            int t = t0 + s;
            float g0 = (float)e0[s];
            float g1 = (float)e1[s];
            float g2 = has2 ? (float)e2[s] : 0.f;
            int tn = t + 4;
            if (tn < 512) {
                const fp16_t* p = px + (size_t)tn * 5120;
                e0[s] = ldg_coh2(p + j0);
                e1[s] = ldg_coh2(p + j0 + 32);
                if (has2) e2[s] = ldg_coh2(p + j0 + 64);
            }
#pragma unroll
            for (int k = 0; k < 20; k++) {
                float hv = he[bl * 21 + k];
                g0 += wr0[k] * hv; g1 += wr1[k] * hv; g2 += wr2[k] * hv;
            }
            gbuf[bl * 81 + j0] = g0;
            gbuf[bl * 81 + j0 + 32] = g1;
            if (has2) gbuf[bl * 81 + j0 + 64] = g2;
            __syncthreads();
            if (p2) {
                float gi = sigm(gbuf[b2 * 81 + u2]);
                float gf = sigm(gbuf[b2 * 81 + u2 + 20]);
                float gg = tanh_(gbuf[b2 * 81 + u2 + 40]);
                float go = sigm(gbuf[b2 * 81 + u2 + 60]);
                float cn2 = gf * c_st + gi * gg;
                float hn = go * tanh_(cn2);
                float p = presf[b2 * 512 + t];
                bool pb = (p != 0.f);
                h_st = pb ? hn : h_st;
                c_st = pb ? cn2 : c_st;
                he[b2 * 21 + u2] = h_st;
            }
            __syncthreads();
            if (tid < 16) {
                float ssum = 0.f;
#pragma unroll
                for (int uu = 0; uu < 20; uu++) ssum += he[tid * 21 + uu] * vvec[M.voff + uu];
                s_out[((b0 + tid) << 9) + t] = ssum;
            }
        }
    }
}

// ---------------------------------------------------------------------------
// Mega kernel: blocks 0..15 = rec (prio 3); blocks 16.. = gemm, XCD-aware
// mapping: all 11 slot-blocks of t-chunk c on XCD c%8 (see R5).
// ---------------------------------------------------------------------------
__global__ __launch_bounds__(512) void mega(MegaArgs A) {
    __shared__ __align__(16) char smem[51712];
    const int tid = threadIdx.x;
    const int bid = blockIdx.x;
    if (bid < 16) {
        __builtin_amdgcn_s_setprio(3);   // protect the serial critical path
        // rec path carve
        float*    presf = (float*)smem;                 // 32768
        bf16_t*   hb0   = (bf16_t*)(smem + 32768);      // 4352
        bf16_t*   hb1   = (bf16_t*)(smem + 37120);      // 4352
        float*    gbuf  = (float*)(smem + 41472);       // 5184
        float*    he    = (float*)(smem + 46656);       // 1344
        unsigned* presw = (unsigned*)(smem + 48000);    // 1024
        int*      wml   = (int*)(smem + 49024);         // 4
        const int mi = bid >> 2, grp = bid & 3;         // 0=L,1=E,2=A,3=I
        const ModRec M = A.rm[mi];
        const int* flagp = A.flags + mi * 128;
        const int need = A.need[mi];
        float* s_out = A.s_out + (size_t)mi * 8 * 64 * 512;
        if (mi == 1)      rec_emot(M, grp, s_out, A.vvec, flagp, need, presf, gbuf, he, wml, tid);
        else if (mi == 2) rec_mfma<64>(M, grp, s_out, A.vvec, flagp, need, presw, hb0, hb1, wml, tid);
        else              rec_mfma<128>(M, grp, s_out, A.vvec, flagp, need, presw, hb0, hb1, wml, tid);
    } else {
        bf16_t* sAh = (bf16_t*)smem;                    // 20480
        bf16_t* sAl = (bf16_t*)(smem + 20480);          // 20480
        bf16_t* sB  = (bf16_t*)(smem + 40960);          // 10240
        int e = bid - 16;            // 176 octets x 8 XCD lanes
        int x = e & 7;               // XCD lane (bid%8 round-robin, perf-only)
        int k = e >> 3;              // stream position on this XCD
        int bmi = (k / 11) * 8 + x;  // t-chunk — all 11 slots same XCD
        int slot = k % 11;
        int mi = A.slot_mi[slot];
        gemm_body(A.gm[mi], A.slot_nb[slot], bmi, mi, A.flags, tid, sAh, sAl, sB);
    }
}

// ---------------------------------------------------------------------------
// Kernel 4: out = mask * (sum of written partial slots + c0)
// slots: L:0-7, E:8, A:16-19, I:24-31
// ---------------------------------------------------------------------------
__global__ void fuse_out(const float* __restrict__ sp, const float* __restrict__ v,
                         const float* __restrict__ masks, float* __restrict__ out) {
    int i = threadIdx.x + blockIdx.x * 256;
    float c0 = v[340];
    float s = 0.f;
#pragma unroll
    for (int w = 0; w < 8; w++) s += sp[(size_t)w * 32768 + i];
    s += sp[(size_t)8 * 32768 + i];
#pragma unroll
    for (int w = 16; w < 20; w++) s += sp[(size_t)w * 32768 + i];
#pragma unroll
    for (int w = 24; w < 32; w++) s += sp[(size_t)w * 32768 + i];
    out[i] = masks[i] * (s + c0);
}

// ---------------------------------------------------------------------------
extern "C" void kernel_launch(void* const* d_in, const int* in_sizes, int n_in,
                              void* d_out, int out_size, void* d_ws, size_t ws_size,
                              hipStream_t stream) {
    const float* xL = (const float*)d_in[0];
    const int*   pL = (const int*)d_in[1];
    const float* WihL = (const float*)d_in[2];
    const float* WhhL = (const float*)d_in[3];
    const float* bihL = (const float*)d_in[4];
    const float* bhhL = (const float*)d_in[5];
    const float* xE = (const float*)d_in[6];
    const int*   pE = (const int*)d_in[7];
    const float* WihE = (const float*)d_in[8];
    const float* WhhE = (const float*)d_in[9];
    const float* bihE = (const float*)d_in[10];
    const float* bhhE = (const float*)d_in[11];
    const float* xA = (const float*)d_in[12];
    const int*   pA = (const int*)d_in[13];
    const float* WihA = (const float*)d_in[14];
    const float* WhhA = (const float*)d_in[15];
    const float* bihA = (const float*)d_in[16];
    const float* bhhA = (const float*)d_in[17];
    const float* xI = (const float*)d_in[18];
    const int*   pI = (const int*)d_in[19];
    const float* WihI = (const float*)d_in[20];
    const float* WhhI = (const float*)d_in[21];
    const float* bihI = (const float*)d_in[22];
    const float* bhhI = (const float*)d_in[23];
    const float* masks = (const float*)d_in[25];
    const float* fW1 = (const float*)d_in[26];
    const float* fb1 = (const float*)d_in[27];
    const float* fW2 = (const float*)d_in[28];
    const float* fb2 = (const float*)d_in[29];

    char* ws = (char*)d_ws;
    float* v     = (float*)ws;                           // 341 floats
    int*   flags = (int*)(ws + 4096);                    // 4*128 ints
    float* spart = (float*)(ws + (1 << 16));             // 32*32768 floats = 4 MB
    fp16_t* xgL = (fp16_t*)(ws + (1 << 16) + (4 << 20));
    fp16_t* xgE = xgL + (size_t)32768 * 512;
    fp16_t* xgA = xgE + (size_t)32768 * 80;
    fp16_t* xgI = xgA + (size_t)32768 * 256;

    prep_fuse<<<dim3(1), dim3(512), 0, stream>>>(fW1, fb1, fW2, fb2, v, flags);

    MegaArgs A;
    A.gm[0] = {xL, WihL, bihL, bhhL, xgL, 300,  10, 512, 7};
    A.gm[1] = {xE, WihE, bihE, bhhE, xgE, 30,   1,  80,  0};
    A.gm[2] = {xA, WihA, bihA, bhhA, xgA, 88,   3,  256, 6};
    A.gm[3] = {xI, WihI, bihI, bhhI, xgI, 1000, 32, 512, 7};
    // I first (largest A-panel gets tightest co-residency), then L, A, E.
    const int mi_tab[11] = {3, 3, 3, 3, 0, 0, 0, 0, 2, 2, 1};
    const int nb_tab[11] = {0, 1, 2, 3, 0, 1, 2, 3, 0, 1, 0};
    for (int i = 0; i < 11; i++) { A.slot_mi[i] = mi_tab[i]; A.slot_nb[i] = nb_tab[i]; }
    A.rm[0] = {WhhL, pL, xgL, 512, 0};
    A.rm[1] = {WhhE, pE, xgE, 80,  128};
    A.rm[2] = {WhhA, pA, xgA, 256, 148};
    A.rm[3] = {WhhI, pI, xgI, 512, 212};
    A.vvec = v;
    A.s_out = spart;
    A.flags = flags;
    A.need[0] = 4; A.need[1] = 1; A.need[2] = 2; A.need[3] = 4;

    mega<<<dim3(16 + 128 * 11), dim3(512), 0, stream>>>(A);

    fuse_out<<<dim3(128), dim3(256), 0, stream>>>(spart, v, masks, (float*)d_out);
}

// Round 8
// 902.966 us; speedup vs baseline: 1.0568x; 1.0211x over previous
//
#include <hip/hip_runtime.h>
#include <stdint.h>

typedef __bf16 bf16_t;
typedef _Float16 fp16_t;
typedef bf16_t bf16x8 __attribute__((ext_vector_type(8)));
typedef fp16_t fp16x4 __attribute__((ext_vector_type(4)));
typedef float f32x4 __attribute__((ext_vector_type(4)));

#define LOG2E 1.44269504088896340736f

__device__ __forceinline__ float sigm(float x) {
    return __builtin_amdgcn_rcpf(1.f + __builtin_amdgcn_exp2f(-LOG2E * x));
}
__device__ __forceinline__ float tanh_(float x) {
    return 1.f - 2.f * __builtin_amdgcn_rcpf(1.f + __builtin_amdgcn_exp2f((2.f * LOG2E) * x));
}

template <int CTRL>
__device__ __forceinline__ float dpp_add(float x) {
    int perm = __builtin_amdgcn_update_dpp(0, __float_as_int(x), CTRL, 0xF, 0xF, true);
    return x + __int_as_float(perm);
}
// Sum across the 16 lanes of a DPP row (our lm group). All lanes get the sum.
__device__ __forceinline__ float red16(float x) {
    x = dpp_add<0xB1>(x);    // quad_perm [1,0,3,2]  : xor 1
    x = dpp_add<0x4E>(x);    // quad_perm [2,3,0,1]  : xor 2
    x = dpp_add<0x124>(x);   // row_ror:4
    x = dpp_add<0x128>(x);   // row_ror:8
    return x;
}

// Coherent (agent-scope, sc0/sc1 per-instruction) loads of producer data.
__device__ __forceinline__ fp16x4 ldg_coh8(const fp16_t* p) {
    unsigned long long v = __hip_atomic_load((const unsigned long long*)p,
                                             __ATOMIC_RELAXED, __HIP_MEMORY_SCOPE_AGENT);
    union { unsigned long long u; fp16x4 f; } c; c.u = v; return c.f;
}
__device__ __forceinline__ fp16_t ldg_coh2(const fp16_t* p) {
    unsigned short v = __hip_atomic_load((const unsigned short*)p,
                                         __ATOMIC_RELAXED, __HIP_MEMORY_SCOPE_AGENT);
    union { unsigned short u; fp16_t f; } c; c.u = v; return c.f;
}

// Consumer gate with register watermark (see R4 notes).
__device__ __forceinline__ void gate_chunk(const int* fp, int need, int cn,
                                           int tid, int* wml, int& wmr) {
    if (cn < wmr) return;
    if (tid == 0) {
        while (__hip_atomic_load(fp + cn, __ATOMIC_RELAXED, __HIP_MEMORY_SCOPE_AGENT) < need)
            __builtin_amdgcn_s_sleep(2);
        int ah = cn + 16; if (ah > 127) ah = 127;
        int nw = (__hip_atomic_load(fp + ah, __ATOMIC_RELAXED, __HIP_MEMORY_SCOPE_AGENT) >= need)
                     ? ah + 1 : cn + 1;
        *wml = nw;
    }
    __syncthreads();
    wmr = *wml;
}

// ---------------------------------------------------------------------------
// Kernel 1: fold fuse_W2@fuse_W1 into a single 340-vector + scalar.
// Also zeroes the chunk flags (stream-ordered before mega).
// ---------------------------------------------------------------------------
__global__ void prep_fuse(const float* __restrict__ W1, const float* __restrict__ b1,
                          const float* __restrict__ W2, const float* __restrict__ b2,
                          float* __restrict__ v, int* __restrict__ flags) {
    int u = threadIdx.x;
    flags[u] = 0;   // 512 ints = 4*128 chunk flags
    if (u < 340) {
        float s = 0.f;
        for (int j = 0; j < 64; j++) s += W2[j] * W1[j * 340 + u];
        v[u] = s;
    } else if (u == 340) {
        float s = 0.f;
        for (int j = 0; j < 64; j++) s += W2[j] * b1[j];
        v[340] = s + b2[0];
    }
}

// ---------------------------------------------------------------------------
// GEMM body. BM=256 rows = one t-chunk of 4 t x 64 b (t-major), BN=128,
// BK=32, split-bf16 A. xg store is row-linear. Completion flag per (mod,bm).
// ---------------------------------------------------------------------------
struct ModGemm {
    const float* x; const float* w; const float* bih; const float* bhh; fp16_t* xg;
    int D; int KB; int N4; int hshift;
};
struct ModRec {
    const float* whh; const int* present; const fp16_t* xg;
    int N4; int voff;
};
struct MegaArgs {
    ModGemm gm[4];
    int slot_mi[11]; int slot_nb[11];
    ModRec rm[4];
    const float* vvec;
    float* s_out;    // [4 mods][8 waves][64 b][512 t]
    int* flags;      // [4][128]
    int need[4];     // gemm blocks per chunk per mod (L4,E1,A2,I4)
};

__device__ void gemm_body(const ModGemm mg, int nb, int bm, int mi,
                          int* __restrict__ flags, int tid,
                          bf16_t* sAh, bf16_t* sAl, bf16_t* sB) {
    const int ncol0 = nb << 7;
    const int w = tid >> 6, l = tid & 63, lm = l & 15, q = l >> 4;
    const int wm = w & 3, wn = w >> 2;        // wave tile: 64 rows x 64 cols
    const int D = mg.D, N4 = mg.N4;
    const int ra = tid >> 1, ca = (tid & 1) << 4;   // A: 2 thr/row, 16 cols
    const int rb = tid >> 2, cb = (tid & 3) << 3;   // B: 4 thr/row, 8 cols

    f32x4 acc[4][4];
#pragma unroll
    for (int a = 0; a < 4; a++)
#pragma unroll
        for (int b = 0; b < 4; b++) acc[a][b] = 0.f;

    for (int kb = 0; kb < mg.KB; kb++) {
        const int k0 = kb << 5;
        // ---- stage A (x): 256 rows (4 t x 64 b), hi/lo split
        {
            long row = (long)(bm << 8) + ra;
            int tt = (int)(row >> 6), bb = (int)(row & 63);
            const float* base = mg.x + ((size_t)bb * 512 + tt) * D;
            const float* src = base + k0 + ca;
            union { bf16_t e[16]; bf16x8 v[2]; } uh, ul;
            if (k0 + ca + 16 <= D) {
#pragma unroll
                for (int j = 0; j < 16; j += 2) {
                    float2 f = *(const float2*)(src + j);
                    bf16_t h0 = (bf16_t)f.x, h1 = (bf16_t)f.y;
                    uh.e[j] = h0; uh.e[j + 1] = h1;
                    ul.e[j] = (bf16_t)(f.x - (float)h0);
                    ul.e[j + 1] = (bf16_t)(f.y - (float)h1);
                }
            } else {
#pragma unroll
                for (int j = 0; j < 16; j++) {
                    int k = k0 + ca + j;
                    float fv = (k < D) ? base[k] : 0.f;
                    bf16_t h0 = (bf16_t)fv;
                    uh.e[j] = h0; ul.e[j] = (bf16_t)(fv - (float)h0);
                }
            }
            *(bf16x8*)&sAh[ra * 40 + ca] = uh.v[0];
            *(bf16x8*)&sAh[ra * 40 + ca + 8] = uh.v[1];
            *(bf16x8*)&sAl[ra * 40 + ca] = ul.v[0];
            *(bf16x8*)&sAl[ra * 40 + ca + 8] = ul.v[1];
        }
        // ---- stage B (W_ih strip): 128 x 32
        {
            int wrow = ncol0 + rb;
            bool vr = wrow < N4;
            const float* src = mg.w + (long)wrow * D + k0 + cb;
            union { bf16_t e[8]; bf16x8 v; } ub;
            if (vr && (k0 + cb + 8 <= D)) {
#pragma unroll
                for (int j = 0; j < 8; j += 2) {
                    float2 f = *(const float2*)(src + j);
                    ub.e[j] = (bf16_t)f.x; ub.e[j + 1] = (bf16_t)f.y;
                }
            } else {
#pragma unroll
                for (int j = 0; j < 8; j++) {
                    int k = k0 + cb + j;
                    ub.e[j] = (vr && k < D) ? (bf16_t)mg.w[(long)wrow * D + k] : (bf16_t)0.f;
                }
            }
            *(bf16x8*)&sB[rb * 40 + cb] = ub.v;
        }
        __syncthreads();
        bf16x8 ah[4], al[4];
#pragma unroll
        for (int mt = 0; mt < 4; mt++) {
            int row = (wm << 6) + (mt << 4) + lm;
            ah[mt] = *(const bf16x8*)&sAh[row * 40 + (q << 3)];
            al[mt] = *(const bf16x8*)&sAl[row * 40 + (q << 3)];
        }
#pragma unroll
        for (int nt = 0; nt < 4; nt++) {
            bf16x8 bfv = *(const bf16x8*)&sB[((wn << 6) + (nt << 4) + lm) * 40 + (q << 3)];
#pragma unroll
            for (int mt = 0; mt < 4; mt++) {
                acc[mt][nt] = __builtin_amdgcn_mfma_f32_16x16x32_bf16(ah[mt], bfv, acc[mt][nt], 0, 0, 0);
                acc[mt][nt] = __builtin_amdgcn_mfma_f32_16x16x32_bf16(al[mt], bfv, acc[mt][nt], 0, 0, 0);
            }
        }
        __syncthreads();
    }
    // ---- epilogue: +(b_ih+b_hh), store fp16 gate-interleaved (row-linear)
#pragma unroll
    for (int nt = 0; nt < 4; nt++) {
        int col = ncol0 + (wn << 6) + (nt << 4) + lm;
        if (col >= N4) continue;
        float bias = mg.bih[col] + mg.bhh[col];
        int colout = mg.hshift ? ((col & ((1 << mg.hshift) - 1)) << 2) | (col >> mg.hshift) : col;
#pragma unroll
        for (int mt = 0; mt < 4; mt++) {
#pragma unroll
            for (int r = 0; r < 4; r++) {
                long row = (long)(bm << 8) + (wm << 6) + (mt << 4) + (q << 2) + r;
                mg.xg[(size_t)row * N4 + colout] = (fp16_t)(acc[mt][nt][r] + bias);
            }
        }
    }
    // ---- completion: barrier drains stores, tid0 release-adds the flag.
    __syncthreads();
    if (tid == 0) {
        __hip_atomic_fetch_add(&flags[mi * 128 + bm], 1, __ATOMIC_RELEASE,
                               __HIP_MEMORY_SCOPE_AGENT);
    }
}

// ---------------------------------------------------------------------------
// Recurrent scan bodies (16 blocks = 4 mods x 4 batch-groups of 16).
// ---------------------------------------------------------------------------
template <int H>
__device__ __forceinline__ void rec_step(
    int t, bool act, int w, int lm, int q, int b0,
    const bf16x8 (&wf)[4][H / 32], float vv,
    fp16x4 (&xvs)[4], const fp16_t* const (&px)[4], size_t tstride,
    float (&h_st)[4], float (&c_st)[4],
    const unsigned (&pw)[4], const bf16_t* __restrict__ hbR,
    bf16_t* __restrict__ hbW, float* __restrict__ s_out) {
    constexpr int KT = H / 32, Hp = H + 8;
    if (act) {
        bf16x8 af[KT];
#pragma unroll
        for (int kt = 0; kt < KT; kt++)
            af[kt] = *(const bf16x8*)&hbR[lm * Hp + (kt << 5) + (q << 3)];
        f32x4 accv[4];
#pragma unroll
        for (int g = 0; g < 4; g++)
#pragma unroll
            for (int r = 0; r < 4; r++)
                accv[g][r] = (float)xvs[r][g];
        int tn = t + 4;
        if (tn < 512) {
#pragma unroll
            for (int r = 0; r < 4; r++)
                xvs[r] = ldg_coh8(px[r] + (size_t)tn * tstride);
        }
#pragma unroll
        for (int kt = 0; kt < KT; kt++)
#pragma unroll
            for (int g = 0; g < 4; g++)
                accv[g] = __builtin_amdgcn_mfma_f32_16x16x32_bf16(af[kt], wf[g][kt], accv[g], 0, 0, 0);
        float cr[4];
#pragma unroll
        for (int r = 0; r < 4; r++) {
            float gi = sigm(accv[0][r]);
            float gf = sigm(accv[1][r]);
            float gg = tanh_(accv[2][r]);
            float go = sigm(accv[3][r]);
            float cn = gf * c_st[r] + gi * gg;
            float hn = go * tanh_(cn);
            bool pb = ((pw[r] >> (t & 31)) & 1u) != 0u;
            h_st[r] = pb ? hn : h_st[r];
            c_st[r] = pb ? cn : c_st[r];
            cr[r] = h_st[r] * vv;
        }
        const int u = (w << 4) + lm;
#pragma unroll
        for (int r = 0; r < 4; r++)
            hbW[((q << 2) + r) * Hp + u] = (bf16_t)h_st[r];
#pragma unroll
        for (int r = 0; r < 4; r++)
            cr[r] = red16(cr[r]);
        if (lm == 0) {
#pragma unroll
            for (int r = 0; r < 4; r++)
                s_out[(size_t)((w << 6) + b0 + (q << 2) + r) * 512 + t] = cr[r];
        }
    }
    __syncthreads();
}

template <int H>
__device__ void rec_mfma(const ModRec M, int grp, float* __restrict__ s_out,
                         const float* __restrict__ vvec,
                         const int* __restrict__ flagp, int need,
                         unsigned* presw, bf16_t* hb0, bf16_t* hb1, int* wml, int tid) {
    constexpr int KT = H / 32, TPG = H / 16, Hp = H + 8;
    const int N4 = 4 * H;
    const int w = tid >> 6, l = tid & 63, lm = l & 15, q = l >> 4;
    const int b0 = grp << 4;
    const bool act = (w < TPG);

    for (int i = tid; i < 16 * Hp; i += 512) { hb0[i] = (bf16_t)0.f; hb1[i] = (bf16_t)0.f; }
    // pack present bits: presw[row][word]  (16 rows x 16 words x 32 bits)
    for (int i = tid; i < 256; i += 512) {
        const int* ps = M.present + ((b0 + (i >> 4)) << 9) + ((i & 15) << 5);
        unsigned bits = 0u;
#pragma unroll
        for (int j = 0; j < 32; j++) bits |= (unsigned)(ps[j] != 0) << j;
        presw[i] = bits;
    }

    bf16x8 wf[4][KT];
    float vv = 0.f;
    const int u = (w << 4) + lm;
    if (act) {
#pragma unroll
        for (int g = 0; g < 4; g++) {
            int n = g * H + u;
#pragma unroll
            for (int kt = 0; kt < KT; kt++) {
                int k = (kt << 5) + (q << 3);
                const float* sp_ = M.whh + (long)n * H + k;
                float4 f0 = *(const float4*)sp_;
                float4 f1 = *(const float4*)(sp_ + 4);
                union { bf16_t e[8]; bf16x8 v; } uu;
                uu.e[0] = (bf16_t)f0.x; uu.e[1] = (bf16_t)f0.y;
                uu.e[2] = (bf16_t)f0.z; uu.e[3] = (bf16_t)f0.w;
                uu.e[4] = (bf16_t)f1.x; uu.e[5] = (bf16_t)f1.y;
                uu.e[6] = (bf16_t)f1.z; uu.e[7] = (bf16_t)f1.w;
                wf[g][kt] = uu.v;
            }
        }
        vv = vvec[M.voff + u];
    }
    const fp16_t* px[4];
#pragma unroll
    for (int r = 0; r < 4; r++)
        px[r] = M.xg + (size_t)(b0 + (q << 2) + r) * N4 + (u << 2);
    const size_t tstride = (size_t)64 * N4;

    int wmr = 0;
    // wait for xg chunk 0 (t=0..3) before the initial prefetch
    gate_chunk(flagp, need, 0, tid, wml, wmr);

    fp16x4 xv[4][4];   // [slot][r]
    if (act) {
#pragma unroll
        for (int s = 0; s < 4; s++)
#pragma unroll
            for (int r = 0; r < 4; r++)
                xv[s][r] = ldg_coh8(px[r] + (size_t)s * tstride);
    }
    float h_st[4] = {0, 0, 0, 0}, c_st[4] = {0, 0, 0, 0};
    unsigned pw[4] = {0, 0, 0, 0};
    __syncthreads();

    for (int t0 = 0; t0 < 512; t0 += 4) {
        int cn = (t0 >> 2) + 1;           // chunk touched by this iter's prefetch
        if (cn < 128) gate_chunk(flagp, need, cn, tid, wml, wmr);
        if ((t0 & 31) == 0 && act) {
            int wd = t0 >> 5;
#pragma unroll
            for (int r = 0; r < 4; r++)
                pw[r] = presw[(((q << 2) + r) << 4) + wd];
        }
        rec_step<H>(t0 + 0, act, w, lm, q, b0, wf, vv, xv[0], px, tstride, h_st, c_st, pw, hb0, hb1, s_out);
        rec_step<H>(t0 + 1, act, w, lm, q, b0, wf, vv, xv[1], px, tstride, h_st, c_st, pw, hb1, hb0, s_out);
        rec_step<H>(t0 + 2, act, w, lm, q, b0, wf, vv, xv[2], px, tstride, h_st, c_st, pw, hb0, hb1, s_out);
        rec_step<H>(t0 + 3, act, w, lm, q, b0, wf, vv, xv[3], px, tstride, h_st, c_st, pw, hb1, hb0, s_out);
    }
}

// Emotient (H=20): fp32 VALU path, weights in registers, prefetch dist 4.
__device__ void rec_emot(const ModRec M, int grp, float* __restrict__ s_out,
                         const float* __restrict__ vvec,
                         const int* __restrict__ flagp, int need,
                         float* presf, float* gbuf /*16*81*/, float* he /*16*21*/,
                         int* wml, int tid) {
    const int b0 = grp << 4;
    for (int i = tid; i < 16 * 21; i += 512) he[i] = 0.f;
    for (int i = tid; i < 16 * 512; i += 512)
        presf[i] = (float)M.present[((b0 + (i >> 9)) << 9) + (i & 511)];
    const int bl = tid >> 5;       // 0..15
    const int j0 = tid & 31;
    const bool has2 = (j0 < 16);
    float wr0[20], wr1[20], wr2[20];
#pragma unroll
    for (int k = 0; k < 20; k++) {
        wr0[k] = M.whh[j0 * 20 + k];
        wr1[k] = M.whh[(j0 + 32) * 20 + k];
        wr2[k] = has2 ? M.whh[(j0 + 64) * 20 + k] : 0.f;
    }
    const int b2 = tid / 20, u2 = tid % 20;
    const bool p2 = (tid < 320);
    float c_st = 0.f, h_st = 0.f;
    const fp16_t* px = M.xg + (size_t)(b0 + bl) * 80;   // + t*64*80

    int wmr = 0;
    gate_chunk(flagp, need, 0, tid, wml, wmr);   // xg chunk 0 ready

    fp16_t e0[4], e1[4], e2[4];
#pragma unroll
    for (int s = 0; s < 4; s++) {
        const fp16_t* p = px + (size_t)s * 5120;
        e0[s] = ldg_coh2(p + j0);
        e1[s] = ldg_coh2(p + j0 + 32);
        e2[s] = has2 ? ldg_coh2(p + j0 + 64) : (fp16_t)0.f;
    }
    __syncthreads();

    for (int t0 = 0; t0 < 512; t0 += 4) {
        int cn = (t0 >> 2) + 1;
        if (cn < 128) gate_chunk(flagp, need, cn, tid, wml, wmr);
#pragma unroll
        for (int s = 0; s < 4; s++) {
            int t = t0 + s;
            float g0 = (float)e0[s];
            float g1 = (float)e1[s];
            float g2 = has2 ? (float)e2[s] : 0.f;
            int tn = t + 4;
            if (tn < 512) {
                const fp16_t* p = px + (size_t)tn * 5120;
                e0[s] = ldg_coh2(p + j0);
                e1[s] = ldg_coh2(p + j0 + 32);
                if (has2) e2[s] = ldg_coh2(p + j0 + 64);
            }
#pragma unroll
            for (int k = 0; k < 20; k++) {
                float hv = he[bl * 21 + k];
                g0 += wr0[k] * hv; g1 += wr1[k] * hv; g2 += wr2[k] * hv;
            }
            gbuf[bl * 81 + j0] = g0;
            gbuf[bl * 81 + j0 + 32] = g1;
            if (has2) gbuf[bl * 81 + j0 + 64] = g2;
            __syncthreads();
            if (p2) {
                float gi = sigm(gbuf[b2 * 81 + u2]);
                float gf = sigm(gbuf[b2 * 81 + u2 + 20]);
                float gg = tanh_(gbuf[b2 * 81 + u2 + 40]);
                float go = sigm(gbuf[b2 * 81 + u2 + 60]);
                float cn2 = gf * c_st + gi * gg;
                float hn = go * tanh_(cn2);
                float p = presf[b2 * 512 + t];
                bool pb = (p != 0.f);
                h_st = pb ? hn : h_st;
                c_st = pb ? cn2 : c_st;
                he[b2 * 21 + u2] = h_st;
            }
            __syncthreads();
            if (tid < 16) {
                float ssum = 0.f;
#pragma unroll
                for (int uu = 0; uu < 20; uu++) ssum += he[tid * 21 + uu] * vvec[M.voff + uu];
                s_out[((b0 + tid) << 9) + t] = ssum;
            }
        }
    }
}

// ---------------------------------------------------------------------------
// Mega kernel: blocks 0..15 = rec (prio 3); blocks 16.. = gemm, XCD-aware
// mapping (see R5). Dynamic LDS = 82,432 B (> 80 KiB) forces 1 block/CU so
// gemm blocks can never co-reside with (and stall) the serial rec blocks.
// ---------------------------------------------------------------------------
__global__ __launch_bounds__(512) void mega(MegaArgs A) {
    extern __shared__ __align__(16) char smem[];
    const int tid = threadIdx.x;
    const int bid = blockIdx.x;
    if (bid < 16) {
        __builtin_amdgcn_s_setprio(3);   // protect the serial critical path
        // rec path carve
        float*    presf = (float*)smem;                 // 32768
        bf16_t*   hb0   = (bf16_t*)(smem + 32768);      // 4352
        bf16_t*   hb1   = (bf16_t*)(smem + 37120);      // 4352
        float*    gbuf  = (float*)(smem + 41472);       // 5184
        float*    he    = (float*)(smem + 46656);       // 1344
        unsigned* presw = (unsigned*)(smem + 48000);    // 1024
        int*      wml   = (int*)(smem + 49024);         // 4
        const int mi = bid >> 2, grp = bid & 3;         // 0=L,1=E,2=A,3=I
        const ModRec M = A.rm[mi];
        const int* flagp = A.flags + mi * 128;
        const int need = A.need[mi];
        float* s_out = A.s_out + (size_t)mi * 8 * 64 * 512;
        if (mi == 1)      rec_emot(M, grp, s_out, A.vvec, flagp, need, presf, gbuf, he, wml, tid);
        else if (mi == 2) rec_mfma<64>(M, grp, s_out, A.vvec, flagp, need, presw, hb0, hb1, wml, tid);
        else              rec_mfma<128>(M, grp, s_out, A.vvec, flagp, need, presw, hb0, hb1, wml, tid);
    } else {
        bf16_t* sAh = (bf16_t*)smem;                    // 20480
        bf16_t* sAl = (bf16_t*)(smem + 20480);          // 20480
        bf16_t* sB  = (bf16_t*)(smem + 40960);          // 10240
        int e = bid - 16;            // 176 octets x 8 XCD lanes
        int x = e & 7;               // XCD lane (bid%8 round-robin, perf-only)
        int k = e >> 3;              // stream position on this XCD
        int bmi = (k / 11) * 8 + x;  // t-chunk — all 11 slots same XCD
        int slot = k % 11;
        int mi = A.slot_mi[slot];
        gemm_body(A.gm[mi], A.slot_nb[slot], bmi, mi, A.flags, tid, sAh, sAl, sB);
    }
}

// ---------------------------------------------------------------------------
// Kernel 4: out = mask * (sum of written partial slots + c0)
// slots: L:0-7, E:8, A:16-19, I:24-31
// ---------------------------------------------------------------------------
__global__ void fuse_out(const float* __restrict__ sp, const float* __restrict__ v,
                         const float* __restrict__ masks, float* __restrict__ out) {
    int i = threadIdx.x + blockIdx.x * 256;
    float c0 = v[340];
    float s = 0.f;
#pragma unroll
    for (int w = 0; w < 8; w++) s += sp[(size_t)w * 32768 + i];
    s += sp[(size_t)8 * 32768 + i];
#pragma unroll
    for (int w = 16; w < 20; w++) s += sp[(size_t)w * 32768 + i];
#pragma unroll
    for (int w = 24; w < 32; w++) s += sp[(size_t)w * 32768 + i];
    out[i] = masks[i] * (s + c0);
}

// ---------------------------------------------------------------------------
extern "C" void kernel_launch(void* const* d_in, const int* in_sizes, int n_in,
                              void* d_out, int out_size, void* d_ws, size_t ws_size,
                              hipStream_t stream) {
    const float* xL = (const float*)d_in[0];
    const int*   pL = (const int*)d_in[1];
    const float* WihL = (const float*)d_in[2];
    const float* WhhL = (const float*)d_in[3];
    const float* bihL = (const float*)d_in[4];
    const float* bhhL = (const float*)d_in[5];
    const float* xE = (const float*)d_in[6];
    const int*   pE = (const int*)d_in[7];
    const float* WihE = (const float*)d_in[8];
    const float* WhhE = (const float*)d_in[9];
    const float* bihE = (const float*)d_in[10];
    const float* bhhE = (const float*)d_in[11];
    const float* xA = (const float*)d_in[12];
    const int*   pA = (const int*)d_in[13];
    const float* WihA = (const float*)d_in[14];
    const float* WhhA = (const float*)d_in[15];
    const float* bihA = (const float*)d_in[16];
    const float* bhhA = (const float*)d_in[17];
    const float* xI = (const float*)d_in[18];
    const int*   pI = (const int*)d_in[19];
    const float* WihI = (const float*)d_in[20];
    const float* WhhI = (const float*)d_in[21];
    const float* bihI = (const float*)d_in[22];
    const float* bhhI = (const float*)d_in[23];
    const float* masks = (const float*)d_in[25];
    const float* fW1 = (const float*)d_in[26];
    const float* fb1 = (const float*)d_in[27];
    const float* fW2 = (const float*)d_in[28];
    const float* fb2 = (const float*)d_in[29];

    char* ws = (char*)d_ws;
    float* v     = (float*)ws;                           // 341 floats
    int*   flags = (int*)(ws + 4096);                    // 4*128 ints
    float* spart = (float*)(ws + (1 << 16));             // 32*32768 floats = 4 MB
    fp16_t* xgL = (fp16_t*)(ws + (1 << 16) + (4 << 20));
    fp16_t* xgE = xgL + (size_t)32768 * 512;
    fp16_t* xgA = xgE + (size_t)32768 * 80;
    fp16_t* xgI = xgA + (size_t)32768 * 256;

    // Allow >64 KiB dynamic LDS for mega (host-side, not stream-captured).
    static bool attr_done = false;
    if (!attr_done) {
        hipFuncSetAttribute((const void*)mega,
                            hipFuncAttributeMaxDynamicSharedMemorySize, 82432);
        attr_done = true;
    }

    prep_fuse<<<dim3(1), dim3(512), 0, stream>>>(fW1, fb1, fW2, fb2, v, flags);

    MegaArgs A;
    A.gm[0] = {xL, WihL, bihL, bhhL, xgL, 300,  10, 512, 7};
    A.gm[1] = {xE, WihE, bihE, bhhE, xgE, 30,   1,  80,  0};
    A.gm[2] = {xA, WihA, bihA, bhhA, xgA, 88,   3,  256, 6};
    A.gm[3] = {xI, WihI, bihI, bhhI, xgI, 1000, 32, 512, 7};
    // I first (largest A-panel gets tightest co-residency), then L, A, E.
    const int mi_tab[11] = {3, 3, 3, 3, 0, 0, 0, 0, 2, 2, 1};
    const int nb_tab[11] = {0, 1, 2, 3, 0, 1, 2, 3, 0, 1, 0};
    for (int i = 0; i < 11; i++) { A.slot_mi[i] = mi_tab[i]; A.slot_nb[i] = nb_tab[i]; }
    A.rm[0] = {WhhL, pL, xgL, 512, 0};
    A.rm[1] = {WhhE, pE, xgE, 80,  128};
    A.rm[2] = {WhhA, pA, xgA, 256, 148};
    A.rm[3] = {WhhI, pI, xgI, 512, 212};
    A.vvec = v;
    A.s_out = spart;
    A.flags = flags;
    A.need[0] = 4; A.need[1] = 1; A.need[2] = 2; A.need[3] = 4;

    mega<<<dim3(16 + 128 * 11), dim3(512), 82432, stream>>>(A);

    fuse_out<<<dim3(128), dim3(256), 0, stream>>>(spart, v, masks, (float*)d_out);
}